// Round 5
// baseline (237.814 us; speedup 1.0000x reference)
//
#include <hip/hip_runtime.h>
#include <hip/hip_bf16.h>

// HierarchicalDistanceLoss: per-row log-softmax CE * distance factor, mean.
// B = 1048576 rows, C = 40 classes (fp32).
// Outputs: out[0] = total_loss, out[1..B] = distance_factor.
//
// R5: revert to the R3 two-kernel structure. R4 (fused fp32 atomicAdd on
// out[0]) FAILED with timing-dependent corruption of out[1..]: on gfx950 the
// per-XCD L2s are not cross-coherent, so an atomic RMW on out[0] and plain
// df stores to out[1..31] create two dirty copies of the same cache line in
// different L2s — whole-line writeback order clobbers one or the other.
// PITFALL: never mix atomic RMW and non-atomic stores from different blocks
// in one cache line; separate with a kernel boundary (the dispatch boundary
// is the flush/acquire point) or a different buffer. The finalize kernel IS
// the coherence mechanism here, not removable overhead.
//
// Main kernel is HBM-bound: 176 MB mandatory traffic at ~6.7 TB/s ≈ 26 µs
// floor; VALU ≈ 4 µs and LDS ≈ 4.3 µs are subordinate (R3 arithmetic).

#define HDL_B 1048576
#define HDL_C 40
#define HDL_ALPHA 0.5f
#define HDL_BLOCK 256
#define HDL_ROWS 256                    // rows per block
#define HDL_GRID (HDL_B / HDL_ROWS)     // 4096, exact
#define HDL_HALF 128                    // rows per staging phase
#define HDL_CSTR (HDL_HALF + 1)         // 129: column stride in words

__global__ __launch_bounds__(HDL_BLOCK, 5)
void hdl_main(const float* __restrict__ logits,
              const int* __restrict__ labels,
              const float* __restrict__ dis,
              float* __restrict__ out,          // out[1..B] = df
              float* __restrict__ bsum) {       // d_ws: one float per block
    __shared__ float tile[HDL_C * HDL_CSTR];    // 20,640 B, column-major [col][local_row]
    __shared__ float wpart[HDL_BLOCK / 64];

    const int tid = threadIdx.x;
    const int row = blockIdx.x * HDL_ROWS + tid;
    const int lab = labels[row];                // coalesced, issued early

    const float4* gsrc = reinterpret_cast<const float4*>(logits)
                         + (size_t)blockIdx.x * (HDL_ROWS * HDL_C / 4);

    // Issue ALL global loads up front: 10 outstanding 16B loads per lane.
    float4 v[5], w[5];
#pragma unroll
    for (int k = 0; k < 5; ++k)
        v[k] = gsrc[tid + HDL_BLOCK * k];                          // phase-0 rows
#pragma unroll
    for (int k = 0; k < 5; ++k)
        w[k] = gsrc[HDL_HALF * HDL_C / 4 + tid + HDL_BLOCK * k];   // phase-1 rows

    float x[HDL_C];
    float xl = 0.0f;
    const int lr_mine = tid & (HDL_HALF - 1);

    // ---- phase 0: scatter rows [0,128) ----
#pragma unroll
    for (int k = 0; k < 5; ++k) {
        const int q = tid + HDL_BLOCK * k;      // [0,1280)
        const int lr = q / 10;                  // local row
        const int c4 = q - lr * 10;             // float4 within row
        const int cb = 4 * c4;                  // starting column
        tile[(cb + 0) * HDL_CSTR + lr] = v[k].x;
        tile[(cb + 1) * HDL_CSTR + lr] = v[k].y;
        tile[(cb + 2) * HDL_CSTR + lr] = v[k].z;
        tile[(cb + 3) * HDL_CSTR + lr] = v[k].w;
    }
    __syncthreads();
    if (tid < HDL_HALF) {                       // wave-uniform
#pragma unroll
        for (int j = 0; j < HDL_C; ++j)
            x[j] = tile[j * HDL_CSTR + lr_mine];    // lanes consecutive: conflict-free
        xl = tile[lab * HDL_CSTR + lr_mine];        // labeled logit
    }
    __syncthreads();

    // ---- phase 1: scatter rows [128,256) ----
#pragma unroll
    for (int k = 0; k < 5; ++k) {
        const int q = tid + HDL_BLOCK * k;
        const int lr = q / 10;
        const int c4 = q - lr * 10;
        const int cb = 4 * c4;
        tile[(cb + 0) * HDL_CSTR + lr] = w[k].x;
        tile[(cb + 1) * HDL_CSTR + lr] = w[k].y;
        tile[(cb + 2) * HDL_CSTR + lr] = w[k].z;
        tile[(cb + 3) * HDL_CSTR + lr] = w[k].w;
    }
    __syncthreads();
    if (tid >= HDL_HALF) {
#pragma unroll
        for (int j = 0; j < HDL_C; ++j)
            x[j] = tile[j * HDL_CSTR + lr_mine];
        xl = tile[lab * HDL_CSTR + lr_mine];
    }
    // no barrier needed: tile is not written again

    // max + argmax (first occurrence, matching jnp.argmax)
    float m = x[0];
    int pred = 0;
#pragma unroll
    for (int j = 1; j < HDL_C; ++j) {
        const bool g = x[j] > m;
        m = g ? x[j] : m;
        pred = g ? j : pred;
    }

    // sum exp(x - m) in base 2: one v_exp_f32 per element
    const float L2E = 1.4426950408889634f;
    const float mL = m * L2E;
    float s = 0.0f;
#pragma unroll
    for (int j = 0; j < HDL_C; ++j)
        s += __builtin_amdgcn_exp2f(__builtin_fmaf(x[j], L2E, -mL));

    // ce = m - x_l + ln(s)
    const float ce = (m - xl) + 0.69314718055994531f * __builtin_amdgcn_logf(s);

    // distance factor: 6.4 KB table is L1-resident after first touch
    const float df = dis[lab * HDL_C + pred] + HDL_ALPHA;
    out[1 + row] = df;

    float val = ce * df;

    // wave64 shuffle reduction -> block partial (separate buffer: no line
    // sharing with d_out — see R4 pitfall above)
#pragma unroll
    for (int o = 32; o > 0; o >>= 1)
        val += __shfl_down(val, o, 64);
    const int lane = tid & 63;
    const int wid = tid >> 6;
    if (lane == 0) wpart[wid] = val;
    __syncthreads();
    if (tid == 0)
        bsum[blockIdx.x] = wpart[0] + wpart[1] + wpart[2] + wpart[3];
}

// Deterministic reduce of the 4096 block partials (no atomics, f64 accumulate).
// Runs after hdl_main's dispatch boundary -> all df stores are globally
// visible before out[0] is written.
__global__ __launch_bounds__(256)
void hdl_finalize(const float* __restrict__ bsum,
                  float* __restrict__ out) {
    __shared__ double dpart[4];
    const int tid = threadIdx.x;
    double v = 0.0;
#pragma unroll
    for (int k = 0; k < HDL_GRID / 256; ++k)    // 16 each
        v += (double)bsum[tid + 256 * k];
#pragma unroll
    for (int o = 32; o > 0; o >>= 1)
        v += __shfl_down(v, o, 64);
    if ((tid & 63) == 0) dpart[tid >> 6] = v;
    __syncthreads();
    if (tid == 0) {
        const double tot = dpart[0] + dpart[1] + dpart[2] + dpart[3];
        out[0] = (float)(tot * (1.0 / (double)HDL_B));
    }
}

extern "C" void kernel_launch(void* const* d_in, const int* in_sizes, int n_in,
                              void* d_out, int out_size, void* d_ws, size_t ws_size,
                              hipStream_t stream) {
    const float* logits = (const float*)d_in[0];
    const int*   labels = (const int*)d_in[1];
    const float* dis    = (const float*)d_in[2];
    float* out  = (float*)d_out;
    float* bsum = (float*)d_ws;   // 4096 floats; fully overwritten every call

    hdl_main<<<HDL_GRID, HDL_BLOCK, 0, stream>>>(logits, labels, dis, out, bsum);
    hdl_finalize<<<1, 256, 0, stream>>>(bsum, out);
}